// Round 6
// baseline (552.395 us; speedup 1.0000x reference)
//
#include <hip/hip_runtime.h>
#include <stdint.h>

#define S_LEN 2048
#define DIMM  2048
#define NH    16
#define NKV   2

typedef __attribute__((ext_vector_type(8))) short s16x8;
typedef __attribute__((ext_vector_type(8))) unsigned short u16x8;
typedef __attribute__((ext_vector_type(4))) float f32x4;
typedef __attribute__((ext_vector_type(4))) unsigned int u32x4;

__device__ __forceinline__ unsigned short f2bf(float f){
  unsigned int u = __builtin_bit_cast(unsigned int, f);
  u += 0x7fffu + ((u >> 16) & 1u);
  return (unsigned short)(u >> 16);
}

__device__ __forceinline__ void gload16(const void* g, void* l){
  __builtin_amdgcn_global_load_lds(
      (const __attribute__((address_space(1))) unsigned int*)g,
      (__attribute__((address_space(3))) unsigned int*)l, 16, 0, 0);
}

// ---------------- fp32 -> bf16 convert ----------------
__global__ __launch_bounds__(256) void cvt_bf16(const float* __restrict__ src,
                                                unsigned short* __restrict__ dst, int n){
  int i = (blockIdx.x * 256 + threadIdx.x) * 8;
  if (i >= n) return;
  const float4* s4 = (const float4*)(src + i);
  float4 a = s4[0], b = s4[1];
  u16x8 o;
  o[0]=f2bf(a.x); o[1]=f2bf(a.y); o[2]=f2bf(a.z); o[3]=f2bf(a.w);
  o[4]=f2bf(b.x); o[5]=f2bf(b.y); o[6]=f2bf(b.z); o[7]=f2bf(b.w);
  *(u16x8*)(dst + i) = o;
}

// ---------------- C = A(bf16,[M,K]) @ W(bf16,[N,K])^T -> fp32 [M,N] ----------------
__global__ __launch_bounds__(256) void gemm_bt(const unsigned short* __restrict__ A,
                                               const unsigned short* __restrict__ W,
                                               float* __restrict__ C,
                                               int M, int N, int K){
  __shared__ __attribute__((aligned(16))) unsigned short As[128*64];
  __shared__ __attribute__((aligned(16))) unsigned short Bs[128*64];
  const int t = threadIdx.x;
  const int lane = t & 63, wave = t >> 6;
  const int l15 = lane & 15, g = lane >> 4;
  const int m0 = blockIdx.y * 128, n0 = blockIdx.x * 128;
  const int wm = (wave >> 1) * 64, wn = (wave & 1) * 64;
  const int srow = t >> 3, sdblk = t & 7;
  const long ldsoff = (long)(t >> 6) * 1024;
  f32x4 acc[4][4] = {};
  for (int k0 = 0; k0 < K; k0 += 64){
    __syncthreads();
    #pragma unroll
    for (int r = 0; r < 4; ++r){
      int row = r*32 + srow;
      int db  = sdblk ^ (row & 7);
      gload16(A + (long)(m0+row)*K + k0 + db*8, (char*)As + r*4096 + ldsoff);
    }
    #pragma unroll
    for (int r = 0; r < 4; ++r){
      int row = r*32 + srow;
      int db  = sdblk ^ (row & 7);
      gload16(W + (long)(n0+row)*K + k0 + db*8, (char*)Bs + r*4096 + ldsoff);
    }
    __syncthreads();
    s16x8 af[4][2], bfr[4][2];
    #pragma unroll
    for (int mi = 0; mi < 4; ++mi)
      #pragma unroll
      for (int kc = 0; kc < 2; ++kc){
        int row = wm + mi*16 + l15;
        int db = (kc*4 + g) ^ (row & 7);
        af[mi][kc] = *(const s16x8*)(As + row*64 + db*8);
      }
    #pragma unroll
    for (int ni = 0; ni < 4; ++ni)
      #pragma unroll
      for (int kc = 0; kc < 2; ++kc){
        int row = wn + ni*16 + l15;
        int db = (kc*4 + g) ^ (row & 7);
        bfr[ni][kc] = *(const s16x8*)(Bs + row*64 + db*8);
      }
    #pragma unroll
    for (int mi = 0; mi < 4; ++mi)
      #pragma unroll
      for (int ni = 0; ni < 4; ++ni)
        #pragma unroll
        for (int kc = 0; kc < 2; ++kc)
          acc[mi][ni] = __builtin_amdgcn_mfma_f32_16x16x32_bf16(af[mi][kc], bfr[ni][kc], acc[mi][ni], 0, 0, 0);
  }
  #pragma unroll
  for (int mi = 0; mi < 4; ++mi)
    #pragma unroll
    for (int ni = 0; ni < 4; ++ni)
      #pragma unroll
      for (int rg = 0; rg < 4; ++rg){
        int row = m0 + wm + mi*16 + g*4 + rg;
        int col = n0 + wn + ni*16 + l15;
        C[(long)row*N + col] = acc[mi][ni][rg];
      }
}

// ---------------- RMSNorm + rotary for Q and K ----------------
// Q gets (1/sqrt(128))*log2(e) folded in => attention exp becomes exp2.
__global__ __launch_bounds__(256) void normrope(const float* __restrict__ qkv,
    const float* __restrict__ cosb, const float* __restrict__ sinb,
    const float* __restrict__ qg, const float* __restrict__ kg,
    unsigned short* __restrict__ q_attn, unsigned short* __restrict__ k_attn){
  int wave = threadIdx.x >> 6, lane = threadIdx.x & 63;
  int rid = blockIdx.x * 4 + wave;
  int d0 = lane * 2;
  const float* src; unsigned short* dst; const float* gm; float sc; int s;
  if (rid < 2*S_LEN*NH){
    int bs = rid >> 4, h = rid & 15;
    int b = bs >> 11; s = bs & 2047;
    src = qkv + (long)bs*2560 + h*128;
    dst = q_attn + ((long)(b*NH + h)*S_LEN + s)*128;
    gm = qg; sc = 0.08838834764831845f * 1.4426950408889634f;  // scale * log2(e)
  } else {
    int r2 = rid - 2*S_LEN*NH;
    int bs = r2 >> 1, kv = r2 & 1;
    int b = bs >> 11; s = bs & 2047;
    src = qkv + (long)bs*2560 + 2048 + kv*128;
    dst = k_attn + ((long)(b*NKV + kv)*S_LEN + s)*128;
    gm = kg; sc = 1.0f;
  }
  float2 x = *(const float2*)(src + d0);
  float ss = x.x*x.x + x.y*x.y;
  #pragma unroll
  for (int m = 1; m < 64; m <<= 1) ss += __shfl_xor(ss, m);
  float r = rsqrtf(ss * (1.0f/128.0f) + 1e-6f);
  float2 gv = *(const float2*)(gm + d0);
  float n0 = x.x * r * gv.x, n1 = x.y * r * gv.y;
  float p0 = __shfl_xor(n0, 32), p1 = __shfl_xor(n1, 32);
  float sgn = (d0 < 64) ? -1.f : 1.f;
  float2 c  = *(const float2*)(cosb + (long)s*128 + d0);
  float2 sn = *(const float2*)(sinb + (long)s*128 + d0);
  float o0 = (n0*c.x + sgn*p0*sn.x) * sc;
  float o1 = (n1*c.y + sgn*p1*sn.y) * sc;
  unsigned int pk = (unsigned int)f2bf(o0) | ((unsigned int)f2bf(o1) << 16);
  *(unsigned int*)(dst + d0) = pk;
}

// ---------------- V: [B,S,KV,128] cols of qkv -> bf16 [B,KV,128,S] (transposed) ----------------
__global__ __launch_bounds__(256) void vtrans(const float* __restrict__ qkv,
                                              unsigned short* __restrict__ v_t){
  __shared__ __attribute__((aligned(16))) unsigned short lds[128*72];
  int bid = blockIdx.x;
  int s0 = (bid & 31) * 64;
  int kv = (bid >> 5) & 1;
  int b  = bid >> 6;
  int t = threadIdx.x;
  #pragma unroll
  for (int it = 0; it < 32; ++it){
    int idx = it*256 + t;
    int s = idx >> 7, d = idx & 127;
    float v = qkv[(long)(b*S_LEN + s0 + s)*2560 + 2304 + kv*128 + d];
    lds[d*72 + s] = f2bf(v);
  }
  __syncthreads();
  #pragma unroll
  for (int it = 0; it < 4; ++it){
    int c = it*256 + t;
    int d = c >> 3, s8 = c & 7;
    u16x8 vv = *(const u16x8*)(lds + d*72 + s8*8);
    *(u16x8*)(v_t + ((long)(b*NKV + kv)*128 + d)*S_LEN + s0 + s8*8) = vv;
  }
}

// ---------------- flash attention (swapped-QK^T; KV tiles split across 2 wave-groups) ----------------
// grid: 32 qt (LPT desc) x 32 (b,h); block 512 = 2 groups x 4 waves x 16 q-rows.
// Group g handles KV tiles ti == g (mod 2), own double-buffered 16KB K region.
// End: flash-merge of the two (m,l,O) partial states via LDS.
__global__ __launch_bounds__(512, 4) void attn_fwd(const unsigned short* __restrict__ q_attn,
    const unsigned short* __restrict__ k_attn, const unsigned short* __restrict__ v_t,
    unsigned short* __restrict__ attn_out, const int* __restrict__ pp){
  __shared__ __attribute__((aligned(16))) char smem[65536];
  const int p = pp[0];
  int bid = blockIdx.x;
  int qt = 31 - (bid >> 5);          // LPT: longest blocks dispatch first
  int bh = bid & 31;
  int h = bh & 15, b = bh >> 4;
  int kvh = h >> 3;
  int t = threadIdx.x, wave = t >> 6, lane = t & 63;
  int wg = wave >> 2, w4 = wave & 3;
  int l15 = lane & 15, g = lane >> 4;
  int qs = qt * 64;
  int qrb = qs + w4*16;
  const unsigned short* qb = q_attn + ((long)(b*NH + h)*S_LEN + qrb + l15)*128;
  s16x8 qf[4];
  #pragma unroll
  for (int kc = 0; kc < 4; ++kc) qf[kc] = *(const s16x8*)(qb + g*8 + kc*32);
  f32x4 O[8] = {};
  float mr = -3e38f, lr = 0.f;       // stats for q-row (qrb + l15), one per lane
  int kv_end = (qs < p) ? ((p > qs+64) ? p : qs+64) : (qs+64);
  int n_tiles = kv_end >> 6;
  int K_it = (n_tiles + 1) >> 1;     // ceil(n/2); group1 idles last iter if n odd
  const unsigned short* kb0 = k_attn + ((long)(b*NKV + kvh)*S_LEN)*128;
  const unsigned short* vb0 = v_t + ((long)(b*NKV + kvh)*128)*S_LEN;
  const int tl = t & 255;            // thread within group
  const int srow16 = tl >> 4, sd16 = tl & 15;
  const long ldsoff = (long)w4 * 1024;
  char* kbase = smem + wg*32768;     // this group's two 16KB K buffers
  const unsigned short* vbase = vb0 + (long)l15*S_LEN + g*8;
  const int iv = qrb + l15;          // this lane's q-row

  // prologue: stage tile index wg into buf 0 (always valid: n_tiles >= 4)
  {
    const unsigned short* kb = kb0 + (long)(wg*64)*128;
    #pragma unroll
    for (int r = 0; r < 4; ++r){
      int j = r*16 + srow16;
      int db = sd16 ^ (j & 7);
      gload16(kb + (long)j*128 + db*8, kbase + r*4096 + ldsoff);
    }
  }
  __syncthreads();

  for (int k = 0; k < K_it; ++k){
    int ti = 2*k + wg;
    int j0 = ti*64;
    bool act = ti < n_tiles;         // wave-uniform
    int buf = k & 1;
    s16x8 vfA[4][2], vfB[4][2];
    if (act){
      // V prefetch batch A (dt 0..3)
      #pragma unroll
      for (int dt = 0; dt < 4; ++dt)
        #pragma unroll
        for (int kc = 0; kc < 2; ++kc)
          vfA[dt][kc] = *(const s16x8*)(vbase + (long)dt*16*S_LEN + j0 + kc*32);
    }
    // stage tile ti+2 into the other buffer (drains at bottom barrier)
    if (ti + 2 < n_tiles){
      const unsigned short* kb = kb0 + (long)(j0 + 128)*128;
      char* dst = kbase + (buf^1)*16384 + ldsoff;
      #pragma unroll
      for (int r = 0; r < 4; ++r){
        int j = r*16 + srow16;
        int db = sd16 ^ (j & 7);
        gload16(kb + (long)j*128 + db*8, dst + r*4096);
      }
    }
    if (act){
      // swapped QK^T: sa[nt] = K_frag * Q_frag
      const unsigned short* ksc = (const unsigned short*)(kbase + buf*16384);
      f32x4 sa[4] = {};
      __builtin_amdgcn_s_setprio(1);
      #pragma unroll
      for (int nt = 0; nt < 4; ++nt){
        int krow = nt*16 + l15;
        #pragma unroll
        for (int kc = 0; kc < 4; ++kc){
          int db = (kc*4 + g) ^ (krow & 7);
          s16x8 kf = *(const s16x8*)(ksc + krow*128 + db*8);
          sa[nt] = __builtin_amdgcn_mfma_f32_16x16x32_bf16(kf, qf[kc], sa[nt], 0, 0, 0);
        }
      }
      __builtin_amdgcn_s_setprio(0);
      // V prefetch batch B (dt 4..7) — lands during softmax
      #pragma unroll
      for (int dt = 0; dt < 4; ++dt)
        #pragma unroll
        for (int kc = 0; kc < 2; ++kc)
          vfB[dt][kc] = *(const s16x8*)(vbase + (long)(dt+4)*16*S_LEN + j0 + kc*32);
      // mask + in-lane row max
      float tm = -3e38f;
      bool full = (j0 + 63 <= qrb) || ((qrb + 15 < p) && (j0 + 63 < p));
      if (full){
        #pragma unroll
        for (int nt = 0; nt < 4; ++nt)
          #pragma unroll
          for (int rg = 0; rg < 4; ++rg) tm = fmaxf(tm, sa[nt][rg]);
      } else {
        #pragma unroll
        for (int nt = 0; nt < 4; ++nt)
          #pragma unroll
          for (int rg = 0; rg < 4; ++rg){
            int j = j0 + nt*16 + g*4 + rg;
            bool ok = (j <= iv) || ((iv < p) && (j < p));
            float sv = ok ? sa[nt][rg] : -3e38f;
            sa[nt][rg] = sv;
            tm = fmaxf(tm, sv);
          }
      }
      tm = fmaxf(tm, __shfl_xor(tm, 16));
      tm = fmaxf(tm, __shfl_xor(tm, 32));
      // online softmax (log2 domain)
      if (!__all(tm <= mr + 8.0f)){       // T13 defer-max
        float nm = fmaxf(mr, tm);
        float sfv = exp2f(mr - nm);
        mr = nm;
        lr *= sfv;
        float sfO[4];
        #pragma unroll
        for (int rg = 0; rg < 4; ++rg)
          sfO[rg] = __shfl(sfv, (lane & 48) | (g*4 + rg));
        #pragma unroll
        for (int dt = 0; dt < 8; ++dt)
          #pragma unroll
          for (int rg = 0; rg < 4; ++rg) O[dt][rg] *= sfO[rg];
      }
      float rs = 0.f;
      #pragma unroll
      for (int nt = 0; nt < 4; ++nt)
        #pragma unroll
        for (int rg = 0; rg < 4; ++rg){
          float e = exp2f(sa[nt][rg] - mr);
          sa[nt][rg] = e;
          rs += e;
        }
      rs += __shfl_xor(rs, 16);
      rs += __shfl_xor(rs, 32);
      lr += rs;
      // pack P rows to bf16 pairs
      unsigned int u[4][2];
      #pragma unroll
      for (int nt = 0; nt < 4; ++nt)
        #pragma unroll
        for (int hh = 0; hh < 2; ++hh){
          float lo = sa[nt][2*hh], hi = sa[nt][2*hh+1];
          unsigned int r;
          asm("v_cvt_pk_bf16_f32 %0, %1, %2" : "=v"(r) : "v"(lo), "v"(hi));
          u[nt][hh] = r;
        }
      // redistribute into PV A-fragments
      s16x8 pf[2];
      #pragma unroll
      for (int kc = 0; kc < 2; ++kc){
        u32x4 w;
        #pragma unroll
        for (int j = 0; j < 4; ++j){
          int srcl = (((2*g + (j>>1)) & 3) << 4) | l15;
          int va = __shfl((int)u[2*kc][j&1],   srcl);
          int vb = __shfl((int)u[2*kc+1][j&1], srcl);
          w[j] = (unsigned int)((g & 2) ? vb : va);
        }
        pf[kc] = __builtin_bit_cast(s16x8, w);
      }
      // PV from prefetched registers
      __builtin_amdgcn_s_setprio(1);
      #pragma unroll
      for (int dt = 0; dt < 4; ++dt)
        #pragma unroll
        for (int kc = 0; kc < 2; ++kc)
          O[dt] = __builtin_amdgcn_mfma_f32_16x16x32_bf16(pf[kc], vfA[dt][kc], O[dt], 0, 0, 0);
      #pragma unroll
      for (int dt = 4; dt < 8; ++dt)
        #pragma unroll
        for (int kc = 0; kc < 2; ++kc)
          O[dt] = __builtin_amdgcn_mfma_f32_16x16x32_bf16(pf[kc], vfB[dt-4][kc], O[dt], 0, 0, 0);
      __builtin_amdgcn_s_setprio(0);
    }
    __syncthreads();   // drains staged loads + frees buffers (both groups)
  }

  // ---- merge the two groups' partial states (K regions are dead now) ----
  float* st = (float*)smem;                         // [8][64][2] = 4KB
  st[(wave*64 + lane)*2 + 0] = mr;
  st[(wave*64 + lane)*2 + 1] = lr;
  __syncthreads();
  float m_o = st[((wave^4)*64 + lane)*2 + 0];
  float l_o = st[((wave^4)*64 + lane)*2 + 1];
  float mm  = fmaxf(mr, m_o);
  float a_s = exp2f(mr - mm);
  float lc  = a_s*lr + exp2f(m_o - mm)*l_o;
  float inv = 1.0f/lc;
  float aO[4], invO[4];
  #pragma unroll
  for (int rg = 0; rg < 4; ++rg){
    int srcl = (lane & 48) | (g*4 + rg);
    aO[rg]   = __shfl(a_s, srcl);
    invO[rg] = __shfl(inv, srcl);
  }
  #pragma unroll
  for (int dt = 0; dt < 8; ++dt)
    #pragma unroll
    for (int rg = 0; rg < 4; ++rg) O[dt][rg] *= aO[rg];
  // group1 ships scaled O through LDS (stride 33 f32: conflict-free b32)
  float* ob = (float*)(smem + 4096) + ((long)(w4*64 + lane))*33;
  if (wg == 1){
    #pragma unroll
    for (int dt = 0; dt < 8; ++dt)
      #pragma unroll
      for (int rg = 0; rg < 4; ++rg) ob[dt*4 + rg] = O[dt][rg];
  }
  __syncthreads();
  if (wg == 0){
    #pragma unroll
    for (int dt = 0; dt < 8; ++dt){
      int col = h*128 + dt*16 + l15;
      #pragma unroll
      for (int rg = 0; rg < 4; ++rg){
        int row = qrb + g*4 + rg;
        float v = (O[dt][rg] + ob[dt*4 + rg]) * invO[rg];
        attn_out[(long)(b*S_LEN + row)*DIMM + col] = f2bf(v);
      }
    }
  }
}

extern "C" void kernel_launch(void* const* d_in, const int* in_sizes, int n_in,
                              void* d_out, int out_size, void* d_ws, size_t ws_size,
                              hipStream_t stream){
  const float* x    = (const float*)d_in[0];
  const float* cosb = (const float*)d_in[1];
  const float* sinb = (const float*)d_in[2];
  const float* wq   = (const float*)d_in[3];
  const float* wk   = (const float*)d_in[4];
  const float* wv   = (const float*)d_in[5];
  const float* wo   = (const float*)d_in[6];
  const float* qg   = (const float*)d_in[7];
  const float* kg   = (const float*)d_in[8];
  const int*   pp   = (const int*)d_in[9];

  char* ws = (char*)d_ws;
  unsigned short* xb    = (unsigned short*)(ws);                 // 4096x2048 bf16
  unsigned short* wqkvb = (unsigned short*)(ws + 16777216);      // 2560x2048 bf16
  unsigned short* wob   = (unsigned short*)(ws + 27262976);      // 2048x2048 bf16
  float*          qkv   = (float*)(ws + 35651584);               // 4096x2560 f32
  unsigned short* qat   = (unsigned short*)(ws + 77594624);      // [B,16,S,128]
  unsigned short* kat   = (unsigned short*)(ws + 94371840);      // [B,2,S,128]
  unsigned short* vt    = (unsigned short*)(ws + 96468992);      // [B,2,128,S]
  unsigned short* aout  = (unsigned short*)(ws + 98566144);      // [B,S,2048]

  cvt_bf16<<<8388608/2048, 256, 0, stream>>>(x,  xb, 8388608);
  cvt_bf16<<<4194304/2048, 256, 0, stream>>>(wq, wqkvb, 4194304);
  cvt_bf16<<< 524288/2048, 256, 0, stream>>>(wk, wqkvb + 4194304, 524288);
  cvt_bf16<<< 524288/2048, 256, 0, stream>>>(wv, wqkvb + 4718592, 524288);
  cvt_bf16<<<4194304/2048, 256, 0, stream>>>(wo, wob, 4194304);

  gemm_bt<<<dim3(2560/128, 4096/128), 256, 0, stream>>>(xb, wqkvb, qkv, 4096, 2560, 2048);
  normrope<<<73728/4, 256, 0, stream>>>(qkv, cosb, sinb, qg, kg, qat, kat);
  vtrans<<<128, 256, 0, stream>>>(qkv, vt);
  attn_fwd<<<1024, 512, 0, stream>>>(qat, kat, vt, aout, pp);
  gemm_bt<<<dim3(2048/128, 4096/128), 256, 0, stream>>>(aout, wob, (float*)d_out, 4096, 2048, 2048);
}

// Round 7
// 343.673 us; speedup vs baseline: 1.6073x; 1.6073x over previous
//
#include <hip/hip_runtime.h>
#include <stdint.h>

#define S_LEN 2048
#define DIMM  2048
#define NH    16
#define NKV   2

typedef __attribute__((ext_vector_type(8))) short s16x8;
typedef __attribute__((ext_vector_type(8))) unsigned short u16x8;
typedef __attribute__((ext_vector_type(4))) float f32x4;
typedef __attribute__((ext_vector_type(4))) unsigned int u32x4;

__device__ __forceinline__ unsigned short f2bf(float f){
  unsigned int u = __builtin_bit_cast(unsigned int, f);
  u += 0x7fffu + ((u >> 16) & 1u);
  return (unsigned short)(u >> 16);
}

__device__ __forceinline__ void gload16(const void* g, void* l){
  __builtin_amdgcn_global_load_lds(
      (const __attribute__((address_space(1))) unsigned int*)g,
      (__attribute__((address_space(3))) unsigned int*)l, 16, 0, 0);
}

// ---------------- fp32 -> bf16 convert ----------------
__global__ __launch_bounds__(256) void cvt_bf16(const float* __restrict__ src,
                                                unsigned short* __restrict__ dst, int n){
  int i = (blockIdx.x * 256 + threadIdx.x) * 8;
  if (i >= n) return;
  const float4* s4 = (const float4*)(src + i);
  float4 a = s4[0], b = s4[1];
  u16x8 o;
  o[0]=f2bf(a.x); o[1]=f2bf(a.y); o[2]=f2bf(a.z); o[3]=f2bf(a.w);
  o[4]=f2bf(b.x); o[5]=f2bf(b.y); o[6]=f2bf(b.z); o[7]=f2bf(b.w);
  *(u16x8*)(dst + i) = o;
}

// ---------------- C = A(bf16,[M,K]) @ W(bf16,[N,K])^T -> fp32 [M,N] ----------------
// 128x128 tile, BK=64, XCD-aware bijective block swizzle (grid%8==0 for all uses).
__global__ __launch_bounds__(256) void gemm_bt(const unsigned short* __restrict__ A,
                                               const unsigned short* __restrict__ W,
                                               float* __restrict__ C,
                                               int M, int N, int K){
  __shared__ __attribute__((aligned(16))) unsigned short As[128*64];
  __shared__ __attribute__((aligned(16))) unsigned short Bs[128*64];
  const int t = threadIdx.x;
  const int lane = t & 63, wave = t >> 6;
  const int l15 = lane & 15, g = lane >> 4;
  // XCD swizzle: consecutive swz ids share an XCD's L2
  const int lid = blockIdx.y * gridDim.x + blockIdx.x;
  const int cpx = (gridDim.x * gridDim.y) >> 3;
  const int swz = (lid & 7) * cpx + (lid >> 3);
  const int m0 = (swz / gridDim.x) * 128, n0 = (swz % gridDim.x) * 128;
  const int wm = (wave >> 1) * 64, wn = (wave & 1) * 64;
  const int srow = t >> 3, sdblk = t & 7;
  const long ldsoff = (long)(t >> 6) * 1024;
  f32x4 acc[4][4] = {};
  for (int k0 = 0; k0 < K; k0 += 64){
    __syncthreads();
    #pragma unroll
    for (int r = 0; r < 4; ++r){
      int row = r*32 + srow;
      int db  = sdblk ^ (row & 7);
      gload16(A + (long)(m0+row)*K + k0 + db*8, (char*)As + r*4096 + ldsoff);
    }
    #pragma unroll
    for (int r = 0; r < 4; ++r){
      int row = r*32 + srow;
      int db  = sdblk ^ (row & 7);
      gload16(W + (long)(n0+row)*K + k0 + db*8, (char*)Bs + r*4096 + ldsoff);
    }
    __syncthreads();
    s16x8 af[4][2], bfr[4][2];
    #pragma unroll
    for (int mi = 0; mi < 4; ++mi)
      #pragma unroll
      for (int kc = 0; kc < 2; ++kc){
        int row = wm + mi*16 + l15;
        int db = (kc*4 + g) ^ (row & 7);
        af[mi][kc] = *(const s16x8*)(As + row*64 + db*8);
      }
    #pragma unroll
    for (int ni = 0; ni < 4; ++ni)
      #pragma unroll
      for (int kc = 0; kc < 2; ++kc){
        int row = wn + ni*16 + l15;
        int db = (kc*4 + g) ^ (row & 7);
        bfr[ni][kc] = *(const s16x8*)(Bs + row*64 + db*8);
      }
    #pragma unroll
    for (int mi = 0; mi < 4; ++mi)
      #pragma unroll
      for (int ni = 0; ni < 4; ++ni)
        #pragma unroll
        for (int kc = 0; kc < 2; ++kc)
          acc[mi][ni] = __builtin_amdgcn_mfma_f32_16x16x32_bf16(af[mi][kc], bfr[ni][kc], acc[mi][ni], 0, 0, 0);
  }
  #pragma unroll
  for (int mi = 0; mi < 4; ++mi)
    #pragma unroll
    for (int ni = 0; ni < 4; ++ni)
      #pragma unroll
      for (int rg = 0; rg < 4; ++rg){
        int row = m0 + wm + mi*16 + g*4 + rg;
        int col = n0 + wn + ni*16 + l15;
        C[(long)row*N + col] = acc[mi][ni][rg];
      }
}

// ---------------- RMSNorm + rotary for Q and K ----------------
// Q gets (1/sqrt(128))*log2(e) folded in => attention exp becomes exp2.
__global__ __launch_bounds__(256) void normrope(const float* __restrict__ qkv,
    const float* __restrict__ cosb, const float* __restrict__ sinb,
    const float* __restrict__ qg, const float* __restrict__ kg,
    unsigned short* __restrict__ q_attn, unsigned short* __restrict__ k_attn){
  int wave = threadIdx.x >> 6, lane = threadIdx.x & 63;
  int rid = blockIdx.x * 4 + wave;
  int d0 = lane * 2;
  const float* src; unsigned short* dst; const float* gm; float sc; int s;
  if (rid < 2*S_LEN*NH){
    int bs = rid >> 4, h = rid & 15;
    int b = bs >> 11; s = bs & 2047;
    src = qkv + (long)bs*2560 + h*128;
    dst = q_attn + ((long)(b*NH + h)*S_LEN + s)*128;
    gm = qg; sc = 0.08838834764831845f * 1.4426950408889634f;  // scale * log2(e)
  } else {
    int r2 = rid - 2*S_LEN*NH;
    int bs = r2 >> 1, kv = r2 & 1;
    int b = bs >> 11; s = bs & 2047;
    src = qkv + (long)bs*2560 + 2048 + kv*128;
    dst = k_attn + ((long)(b*NKV + kv)*S_LEN + s)*128;
    gm = kg; sc = 1.0f;
  }
  float2 x = *(const float2*)(src + d0);
  float ss = x.x*x.x + x.y*x.y;
  #pragma unroll
  for (int m = 1; m < 64; m <<= 1) ss += __shfl_xor(ss, m);
  float r = rsqrtf(ss * (1.0f/128.0f) + 1e-6f);
  float2 gv = *(const float2*)(gm + d0);
  float n0 = x.x * r * gv.x, n1 = x.y * r * gv.y;
  float p0 = __shfl_xor(n0, 32), p1 = __shfl_xor(n1, 32);
  float sgn = (d0 < 64) ? -1.f : 1.f;
  float2 c  = *(const float2*)(cosb + (long)s*128 + d0);
  float2 sn = *(const float2*)(sinb + (long)s*128 + d0);
  float o0 = (n0*c.x + sgn*p0*sn.x) * sc;
  float o1 = (n1*c.y + sgn*p1*sn.y) * sc;
  unsigned int pk = (unsigned int)f2bf(o0) | ((unsigned int)f2bf(o1) << 16);
  *(unsigned int*)(dst + d0) = pk;
}

// ---------------- V: [B,S,KV,128] cols of qkv -> bf16 [B,KV,128,S] (transposed) ----------------
__global__ __launch_bounds__(256) void vtrans(const float* __restrict__ qkv,
                                              unsigned short* __restrict__ v_t){
  __shared__ __attribute__((aligned(16))) unsigned short lds[128*72];
  int bid = blockIdx.x;
  int s0 = (bid & 31) * 64;
  int kv = (bid >> 5) & 1;
  int b  = bid >> 6;
  int t = threadIdx.x;
  #pragma unroll
  for (int it = 0; it < 32; ++it){
    int idx = it*256 + t;
    int s = idx >> 7, d = idx & 127;
    float v = qkv[(long)(b*S_LEN + s0 + s)*2560 + 2304 + kv*128 + d];
    lds[d*72 + s] = f2bf(v);
  }
  __syncthreads();
  #pragma unroll
  for (int it = 0; it < 4; ++it){
    int c = it*256 + t;
    int d = c >> 3, s8 = c & 7;
    u16x8 vv = *(const u16x8*)(lds + d*72 + s8*8);
    *(u16x8*)(v_t + ((long)(b*NKV + kv)*128 + d)*S_LEN + s0 + s8*8) = vv;
  }
}

// ---------------- flash attention (swapped-QK^T; paired Q-tiles, 256-thread blocks) ----------------
// grid: 512 = 16 pairs x 32 (b,h); block 256 = 4 waves x 16 q-rows. KVB=64.
// Block (pair,bh) runs Q-tiles {pair, 31-pair} sequentially: 33-36 tiles for
// every block => constant 2 blocks/CU, no straggler tail. Body identical to the
// verified round-4 kernel (VGPR ~104, no spills).
__global__ __launch_bounds__(256) void attn_fwd(const unsigned short* __restrict__ q_attn,
    const unsigned short* __restrict__ k_attn, const unsigned short* __restrict__ v_t,
    unsigned short* __restrict__ attn_out, const int* __restrict__ pp){
  __shared__ __attribute__((aligned(16))) unsigned short Ks[2][64*128];
  const int p = pp[0];
  int bid = blockIdx.x;
  int pair = bid >> 5;               // 0..15
  int bh = bid & 31;                 // 0..31
  int h = bh & 15, b = bh >> 4;
  int kvh = h >> 3;
  int t = threadIdx.x, wave = t >> 6, lane = t & 63;
  int l15 = lane & 15, g = lane >> 4;
  const unsigned short* kb0 = k_attn + ((long)(b*NKV + kvh)*S_LEN)*128;
  const unsigned short* vb0 = v_t + ((long)(b*NKV + kvh)*128)*S_LEN;
  const int srow16 = t >> 4, sd16 = t & 15;
  const long ldsoff = (long)wave * 1024;
  const unsigned short* vbase = vb0 + (long)l15*S_LEN + g*8;
  int cur = 0;

  #pragma unroll 1
  for (int half = 0; half < 2; ++half){
    int qt = half ? (31 - pair) : pair;
    int qs = qt * 64;
    int qrb = qs + wave*16;
    const unsigned short* qb = q_attn + ((long)(b*NH + h)*S_LEN + qrb + l15)*128;
    s16x8 qf[4];
    #pragma unroll
    for (int kc = 0; kc < 4; ++kc) qf[kc] = *(const s16x8*)(qb + g*8 + kc*32);
    f32x4 O[8] = {};
    float mr = -3e38f, lr = 0.f;     // stats for q-row (qrb + l15), one per lane
    int kv_end = (qs < p) ? ((p > qs+64) ? p : qs+64) : (qs+64);
    const int iv = qrb + l15;        // this lane's q-row

    // prologue: stage tile 0 into Ks[cur]
    #pragma unroll
    for (int r = 0; r < 4; ++r){
      int j = r*16 + srow16;
      int db = sd16 ^ (j & 7);
      gload16(kb0 + (long)j*128 + db*8, (char*)Ks[cur] + r*4096 + ldsoff);
    }
    __syncthreads();

    #pragma unroll 1
    for (int j0 = 0; j0 < kv_end; j0 += 64){
      // V prefetch batch A (dt 0..3) into registers
      s16x8 vfA[4][2];
      #pragma unroll
      for (int dt = 0; dt < 4; ++dt)
        #pragma unroll
        for (int kc = 0; kc < 2; ++kc)
          vfA[dt][kc] = *(const s16x8*)(vbase + (long)dt*16*S_LEN + j0 + kc*32);
      // stage NEXT K tile (drains at the bottom barrier)
      if (j0 + 64 < kv_end){
        const unsigned short* kb = kb0 + (long)(j0 + 64)*128;
        char* dst = (char*)Ks[cur^1] + ldsoff;
        #pragma unroll
        for (int r = 0; r < 4; ++r){
          int j = r*16 + srow16;
          int db = sd16 ^ (j & 7);
          gload16(kb + (long)j*128 + db*8, dst + r*4096);
        }
      }
      // swapped QK^T: sa[nt] = K_frag * Q_frag  => S^T tile
      const unsigned short* ksc = Ks[cur];
      f32x4 sa[4] = {};
      __builtin_amdgcn_s_setprio(1);
      #pragma unroll
      for (int nt = 0; nt < 4; ++nt){
        int krow = nt*16 + l15;
        #pragma unroll
        for (int kc = 0; kc < 4; ++kc){
          int db = (kc*4 + g) ^ (krow & 7);
          s16x8 kf = *(const s16x8*)(ksc + krow*128 + db*8);
          sa[nt] = __builtin_amdgcn_mfma_f32_16x16x32_bf16(kf, qf[kc], sa[nt], 0, 0, 0);
        }
      }
      __builtin_amdgcn_s_setprio(0);
      // V prefetch batch B (dt 4..7) — lands during softmax
      s16x8 vfB[4][2];
      #pragma unroll
      for (int dt = 0; dt < 4; ++dt)
        #pragma unroll
        for (int kc = 0; kc < 2; ++kc)
          vfB[dt][kc] = *(const s16x8*)(vbase + (long)(dt+4)*16*S_LEN + j0 + kc*32);
      // mask + in-lane row max (all 16 values belong to q-row iv)
      float tm = -3e38f;
      bool full = (j0 + 63 <= qrb) || ((qrb + 15 < p) && (j0 + 63 < p));
      if (full){
        #pragma unroll
        for (int nt = 0; nt < 4; ++nt)
          #pragma unroll
          for (int rg = 0; rg < 4; ++rg) tm = fmaxf(tm, sa[nt][rg]);
      } else {
        #pragma unroll
        for (int nt = 0; nt < 4; ++nt)
          #pragma unroll
          for (int rg = 0; rg < 4; ++rg){
            int j = j0 + nt*16 + g*4 + rg;
            bool ok = (j <= iv) || ((iv < p) && (j < p));
            float sv = ok ? sa[nt][rg] : -3e38f;
            sa[nt][rg] = sv;
            tm = fmaxf(tm, sv);
          }
      }
      tm = fmaxf(tm, __shfl_xor(tm, 16));
      tm = fmaxf(tm, __shfl_xor(tm, 32));
      // online softmax (log2 domain; scale*log2e pre-folded into Q)
      if (!__all(tm <= mr + 8.0f)){       // T13 defer-max
        float nm = fmaxf(mr, tm);
        float sfv = exp2f(mr - nm);
        mr = nm;
        lr *= sfv;
        float sfO[4];
        #pragma unroll
        for (int rg = 0; rg < 4; ++rg)
          sfO[rg] = __shfl(sfv, (lane & 48) | (g*4 + rg));
        #pragma unroll
        for (int dt = 0; dt < 8; ++dt)
          #pragma unroll
          for (int rg = 0; rg < 4; ++rg) O[dt][rg] *= sfO[rg];
      }
      float rs = 0.f;
      #pragma unroll
      for (int nt = 0; nt < 4; ++nt)
        #pragma unroll
        for (int rg = 0; rg < 4; ++rg){
          float e = exp2f(sa[nt][rg] - mr);
          sa[nt][rg] = e;
          rs += e;
        }
      rs += __shfl_xor(rs, 16);
      rs += __shfl_xor(rs, 32);
      lr += rs;
      // pack P rows to bf16 pairs
      unsigned int u[4][2];
      #pragma unroll
      for (int nt = 0; nt < 4; ++nt)
        #pragma unroll
        for (int hh = 0; hh < 2; ++hh){
          float lo = sa[nt][2*hh], hi = sa[nt][2*hh+1];
          unsigned int r;
          asm("v_cvt_pk_bf16_f32 %0, %1, %2" : "=v"(r) : "v"(lo), "v"(hi));
          u[nt][hh] = r;
        }
      // redistribute into PV A-fragments
      s16x8 pf[2];
      #pragma unroll
      for (int kc = 0; kc < 2; ++kc){
        u32x4 w;
        #pragma unroll
        for (int j = 0; j < 4; ++j){
          int srcl = (((2*g + (j>>1)) & 3) << 4) | l15;
          int va = __shfl((int)u[2*kc][j&1],   srcl);
          int vb = __shfl((int)u[2*kc+1][j&1], srcl);
          w[j] = (unsigned int)((g & 2) ? vb : va);
        }
        pf[kc] = __builtin_bit_cast(s16x8, w);
      }
      // PV from prefetched registers
      __builtin_amdgcn_s_setprio(1);
      #pragma unroll
      for (int dt = 0; dt < 4; ++dt)
        #pragma unroll
        for (int kc = 0; kc < 2; ++kc)
          O[dt] = __builtin_amdgcn_mfma_f32_16x16x32_bf16(pf[kc], vfA[dt][kc], O[dt], 0, 0, 0);
      #pragma unroll
      for (int dt = 4; dt < 8; ++dt)
        #pragma unroll
        for (int kc = 0; kc < 2; ++kc)
          O[dt] = __builtin_amdgcn_mfma_f32_16x16x32_bf16(pf[kc], vfB[dt-4][kc], O[dt], 0, 0, 0);
      __builtin_amdgcn_s_setprio(0);
      __syncthreads();   // drains next-tile stage + frees Ks[cur]
      cur ^= 1;
    }
    // epilogue: redistribute 1/lr from l15-domain to O-domain
    float inv = 1.0f / lr;
    float invO[4];
    #pragma unroll
    for (int rg = 0; rg < 4; ++rg)
      invO[rg] = __shfl(inv, (lane & 48) | (g*4 + rg));
    #pragma unroll
    for (int dt = 0; dt < 8; ++dt)
      #pragma unroll
      for (int rg = 0; rg < 4; ++rg){
        int row = qrb + g*4 + rg;
        int col = h*128 + dt*16 + l15;
        attn_out[(long)(b*S_LEN + row)*DIMM + col] = f2bf(O[dt][rg]*invO[rg]);
      }
  }
}

extern "C" void kernel_launch(void* const* d_in, const int* in_sizes, int n_in,
                              void* d_out, int out_size, void* d_ws, size_t ws_size,
                              hipStream_t stream){
  const float* x    = (const float*)d_in[0];
  const float* cosb = (const float*)d_in[1];
  const float* sinb = (const float*)d_in[2];
  const float* wq   = (const float*)d_in[3];
  const float* wk   = (const float*)d_in[4];
  const float* wv   = (const float*)d_in[5];
  const float* wo   = (const float*)d_in[6];
  const float* qg   = (const float*)d_in[7];
  const float* kg   = (const float*)d_in[8];
  const int*   pp   = (const int*)d_in[9];

  char* ws = (char*)d_ws;
  unsigned short* xb    = (unsigned short*)(ws);                 // 4096x2048 bf16
  unsigned short* wqkvb = (unsigned short*)(ws + 16777216);      // 2560x2048 bf16
  unsigned short* wob   = (unsigned short*)(ws + 27262976);      // 2048x2048 bf16
  float*          qkv   = (float*)(ws + 35651584);               // 4096x2560 f32
  unsigned short* qat   = (unsigned short*)(ws + 77594624);      // [B,16,S,128]
  unsigned short* kat   = (unsigned short*)(ws + 94371840);      // [B,2,S,128]
  unsigned short* vt    = (unsigned short*)(ws + 96468992);      // [B,2,128,S]
  unsigned short* aout  = (unsigned short*)(ws + 98566144);      // [B,S,2048]

  cvt_bf16<<<8388608/2048, 256, 0, stream>>>(x,  xb, 8388608);
  cvt_bf16<<<4194304/2048, 256, 0, stream>>>(wq, wqkvb, 4194304);
  cvt_bf16<<< 524288/2048, 256, 0, stream>>>(wk, wqkvb + 4194304, 524288);
  cvt_bf16<<< 524288/2048, 256, 0, stream>>>(wv, wqkvb + 4718592, 524288);
  cvt_bf16<<<4194304/2048, 256, 0, stream>>>(wo, wob, 4194304);

  gemm_bt<<<dim3(2560/128, 4096/128), 256, 0, stream>>>(xb, wqkvb, qkv, 4096, 2560, 2048);
  normrope<<<73728/4, 256, 0, stream>>>(qkv, cosb, sinb, qg, kg, qat, kat);
  vtrans<<<128, 256, 0, stream>>>(qkv, vt);
  attn_fwd<<<512, 256, 0, stream>>>(qat, kat, vt, aout, pp);
  gemm_bt<<<dim3(2048/128, 4096/128), 256, 0, stream>>>(aout, wob, (float*)d_out, 4096, 2048, 2048);
}

// Round 8
// 325.239 us; speedup vs baseline: 1.6984x; 1.0567x over previous
//
#include <hip/hip_runtime.h>
#include <stdint.h>

#define S_LEN 2048
#define DIMM  2048
#define NH    16
#define NKV   2

typedef __attribute__((ext_vector_type(8))) short s16x8;
typedef __attribute__((ext_vector_type(8))) unsigned short u16x8;
typedef __attribute__((ext_vector_type(4))) float f32x4;
typedef __attribute__((ext_vector_type(4))) unsigned int u32x4;

__device__ __forceinline__ unsigned short f2bf(float f){
  unsigned int u = __builtin_bit_cast(unsigned int, f);
  u += 0x7fffu + ((u >> 16) & 1u);
  return (unsigned short)(u >> 16);
}

__device__ __forceinline__ void gload16(const void* g, void* l){
  __builtin_amdgcn_global_load_lds(
      (const __attribute__((address_space(1))) unsigned int*)g,
      (__attribute__((address_space(3))) unsigned int*)l, 16, 0, 0);
}

// ---------------- fp32 -> bf16 convert ----------------
__global__ __launch_bounds__(256) void cvt_bf16(const float* __restrict__ src,
                                                unsigned short* __restrict__ dst, int n){
  int i = (blockIdx.x * 256 + threadIdx.x) * 8;
  if (i >= n) return;
  const float4* s4 = (const float4*)(src + i);
  float4 a = s4[0], b = s4[1];
  u16x8 o;
  o[0]=f2bf(a.x); o[1]=f2bf(a.y); o[2]=f2bf(a.z); o[3]=f2bf(a.w);
  o[4]=f2bf(b.x); o[5]=f2bf(b.y); o[6]=f2bf(b.z); o[7]=f2bf(b.w);
  *(u16x8*)(dst + i) = o;
}

// ---------------- C = A(bf16,[M,K]) @ W(bf16,[N,K])^T -> fp32 [M,N] ----------------
// 128x128 tile, BK=64, XCD-aware bijective block swizzle (grid%8==0 for all uses).
__global__ __launch_bounds__(256) void gemm_bt(const unsigned short* __restrict__ A,
                                               const unsigned short* __restrict__ W,
                                               float* __restrict__ C,
                                               int M, int N, int K){
  __shared__ __attribute__((aligned(16))) unsigned short As[128*64];
  __shared__ __attribute__((aligned(16))) unsigned short Bs[128*64];
  const int t = threadIdx.x;
  const int lane = t & 63, wave = t >> 6;
  const int l15 = lane & 15, g = lane >> 4;
  const int lid = blockIdx.y * gridDim.x + blockIdx.x;
  const int cpx = (gridDim.x * gridDim.y) >> 3;
  const int swz = (lid & 7) * cpx + (lid >> 3);
  const int m0 = (swz / gridDim.x) * 128, n0 = (swz % gridDim.x) * 128;
  const int wm = (wave >> 1) * 64, wn = (wave & 1) * 64;
  const int srow = t >> 3, sdblk = t & 7;
  const long ldsoff = (long)(t >> 6) * 1024;
  f32x4 acc[4][4] = {};
  for (int k0 = 0; k0 < K; k0 += 64){
    __syncthreads();
    #pragma unroll
    for (int r = 0; r < 4; ++r){
      int row = r*32 + srow;
      int db  = sdblk ^ (row & 7);
      gload16(A + (long)(m0+row)*K + k0 + db*8, (char*)As + r*4096 + ldsoff);
    }
    #pragma unroll
    for (int r = 0; r < 4; ++r){
      int row = r*32 + srow;
      int db  = sdblk ^ (row & 7);
      gload16(W + (long)(n0+row)*K + k0 + db*8, (char*)Bs + r*4096 + ldsoff);
    }
    __syncthreads();
    s16x8 af[4][2], bfr[4][2];
    #pragma unroll
    for (int mi = 0; mi < 4; ++mi)
      #pragma unroll
      for (int kc = 0; kc < 2; ++kc){
        int row = wm + mi*16 + l15;
        int db = (kc*4 + g) ^ (row & 7);
        af[mi][kc] = *(const s16x8*)(As + row*64 + db*8);
      }
    #pragma unroll
    for (int ni = 0; ni < 4; ++ni)
      #pragma unroll
      for (int kc = 0; kc < 2; ++kc){
        int row = wn + ni*16 + l15;
        int db = (kc*4 + g) ^ (row & 7);
        bfr[ni][kc] = *(const s16x8*)(Bs + row*64 + db*8);
      }
    #pragma unroll
    for (int mi = 0; mi < 4; ++mi)
      #pragma unroll
      for (int ni = 0; ni < 4; ++ni)
        #pragma unroll
        for (int kc = 0; kc < 2; ++kc)
          acc[mi][ni] = __builtin_amdgcn_mfma_f32_16x16x32_bf16(af[mi][kc], bfr[ni][kc], acc[mi][ni], 0, 0, 0);
  }
  #pragma unroll
  for (int mi = 0; mi < 4; ++mi)
    #pragma unroll
    for (int ni = 0; ni < 4; ++ni)
      #pragma unroll
      for (int rg = 0; rg < 4; ++rg){
        int row = m0 + wm + mi*16 + g*4 + rg;
        int col = n0 + wn + ni*16 + l15;
        C[(long)row*N + col] = acc[mi][ni][rg];
      }
}

// ---------------- RMSNorm + rotary for Q and K ----------------
// Q gets (1/sqrt(128))*log2(e) folded in => attention exp becomes exp2.
__global__ __launch_bounds__(256) void normrope(const float* __restrict__ qkv,
    const float* __restrict__ cosb, const float* __restrict__ sinb,
    const float* __restrict__ qg, const float* __restrict__ kg,
    unsigned short* __restrict__ q_attn, unsigned short* __restrict__ k_attn){
  int wave = threadIdx.x >> 6, lane = threadIdx.x & 63;
  int rid = blockIdx.x * 4 + wave;
  int d0 = lane * 2;
  const float* src; unsigned short* dst; const float* gm; float sc; int s;
  if (rid < 2*S_LEN*NH){
    int bs = rid >> 4, h = rid & 15;
    int b = bs >> 11; s = bs & 2047;
    src = qkv + (long)bs*2560 + h*128;
    dst = q_attn + ((long)(b*NH + h)*S_LEN + s)*128;
    gm = qg; sc = 0.08838834764831845f * 1.4426950408889634f;  // scale * log2(e)
  } else {
    int r2 = rid - 2*S_LEN*NH;
    int bs = r2 >> 1, kv = r2 & 1;
    int b = bs >> 11; s = bs & 2047;
    src = qkv + (long)bs*2560 + 2048 + kv*128;
    dst = k_attn + ((long)(b*NKV + kv)*S_LEN + s)*128;
    gm = kg; sc = 1.0f;
  }
  float2 x = *(const float2*)(src + d0);
  float ss = x.x*x.x + x.y*x.y;
  #pragma unroll
  for (int m = 1; m < 64; m <<= 1) ss += __shfl_xor(ss, m);
  float r = rsqrtf(ss * (1.0f/128.0f) + 1e-6f);
  float2 gv = *(const float2*)(gm + d0);
  float n0 = x.x * r * gv.x, n1 = x.y * r * gv.y;
  float p0 = __shfl_xor(n0, 32), p1 = __shfl_xor(n1, 32);
  float sgn = (d0 < 64) ? -1.f : 1.f;
  float2 c  = *(const float2*)(cosb + (long)s*128 + d0);
  float2 sn = *(const float2*)(sinb + (long)s*128 + d0);
  float o0 = (n0*c.x + sgn*p0*sn.x) * sc;
  float o1 = (n1*c.y + sgn*p1*sn.y) * sc;
  unsigned int pk = (unsigned int)f2bf(o0) | ((unsigned int)f2bf(o1) << 16);
  *(unsigned int*)(dst + d0) = pk;
}

// ---------------- V: [B,S,KV,128] cols of qkv -> bf16 [B,KV,128,S] (transposed) ----------------
__global__ __launch_bounds__(256) void vtrans(const float* __restrict__ qkv,
                                              unsigned short* __restrict__ v_t){
  __shared__ __attribute__((aligned(16))) unsigned short lds[128*72];
  int bid = blockIdx.x;
  int s0 = (bid & 31) * 64;
  int kv = (bid >> 5) & 1;
  int b  = bid >> 6;
  int t = threadIdx.x;
  #pragma unroll
  for (int it = 0; it < 32; ++it){
    int idx = it*256 + t;
    int s = idx >> 7, d = idx & 127;
    float v = qkv[(long)(b*S_LEN + s0 + s)*2560 + 2304 + kv*128 + d];
    lds[d*72 + s] = f2bf(v);
  }
  __syncthreads();
  #pragma unroll
  for (int it = 0; it < 4; ++it){
    int c = it*256 + t;
    int d = c >> 3, s8 = c & 7;
    u16x8 vv = *(const u16x8*)(lds + d*72 + s8*8);
    *(u16x8*)(v_t + ((long)(b*NKV + kv)*128 + d)*S_LEN + s0 + s8*8) = vv;
  }
}

// ---------------- flash attention (swapped-QK^T; KV-split flash-decoding) ----------------
// grid 1536: bid<1024 -> split blocks: qt=31-(bid>>6) (desc), chunk=(bid>>5)&1, bh=bid&31;
//            else unsplit: qt=15-(e>>5), bh=e&31. Chains <=16 tiles everywhere + refill.
// Split blocks write unnormalized partials (O f32 [64][128] + m,l per row, log2 domain)
// to workspace; attn_merge combines. Body identical to verified round-4 kernel.
__global__ __launch_bounds__(256) void attn_fwd(const unsigned short* __restrict__ q_attn,
    const unsigned short* __restrict__ k_attn, const unsigned short* __restrict__ v_t,
    unsigned short* __restrict__ attn_out, float* __restrict__ part,
    const int* __restrict__ pp){
  __shared__ __attribute__((aligned(16))) unsigned short Ks[2][64*128];
  const int p = pp[0];
  int bid = blockIdx.x;
  int qt, bh, chunk; bool split;
  if (bid < 1024){
    split = true;
    qt = 31 - (bid >> 6);
    chunk = (bid >> 5) & 1;
    bh = bid & 31;
  } else {
    split = false;
    int e = bid - 1024;
    qt = 15 - (e >> 5);
    chunk = 0;
    bh = e & 31;
  }
  int h = bh & 15, b = bh >> 4;
  int kvh = h >> 3;
  int t = threadIdx.x, wave = t >> 6, lane = t & 63;
  int l15 = lane & 15, g = lane >> 4;
  int qs = qt * 64;
  int qrb = qs + wave*16;
  const unsigned short* qb = q_attn + ((long)(b*NH + h)*S_LEN + qrb + l15)*128;
  s16x8 qf[4];
  #pragma unroll
  for (int kc = 0; kc < 4; ++kc) qf[kc] = *(const s16x8*)(qb + g*8 + kc*32);
  f32x4 O[8] = {};
  float mr = -3e38f, lr = 0.f;       // stats for q-row (qrb + l15), one per lane
  int kv_end = (qs < p) ? ((p > qs+64) ? p : qs+64) : (qs+64);
  int n  = (kv_end + 63) >> 6;
  int n0 = (n + 1) >> 1;
  int tbeg = (split && chunk) ? n0 : 0;
  int tend = split ? (chunk ? n : n0) : n;
  const unsigned short* kb0 = k_attn + ((long)(b*NKV + kvh)*S_LEN)*128;
  const unsigned short* vb0 = v_t + ((long)(b*NKV + kvh)*128)*S_LEN;
  const int srow16 = t >> 4, sd16 = t & 15;
  const long ldsoff = (long)wave * 1024;
  const unsigned short* vbase = vb0 + (long)l15*S_LEN + g*8;
  const int iv = qrb + l15;          // this lane's q-row

  // prologue: stage tile tbeg into Ks[0]
  {
    const unsigned short* kb = kb0 + (long)(tbeg*64)*128;
    #pragma unroll
    for (int r = 0; r < 4; ++r){
      int j = r*16 + srow16;
      int db = sd16 ^ (j & 7);
      gload16(kb + (long)j*128 + db*8, (char*)Ks[0] + r*4096 + ldsoff);
    }
  }
  __syncthreads();
  int cur = 0;

  #pragma unroll 1
  for (int ti = tbeg; ti < tend; ++ti){
    int j0 = ti*64;
    // V prefetch batch A (dt 0..3) into registers
    s16x8 vfA[4][2];
    #pragma unroll
    for (int dt = 0; dt < 4; ++dt)
      #pragma unroll
      for (int kc = 0; kc < 2; ++kc)
        vfA[dt][kc] = *(const s16x8*)(vbase + (long)dt*16*S_LEN + j0 + kc*32);
    // stage NEXT K tile (drains at the bottom barrier)
    if (ti + 1 < tend){
      const unsigned short* kb = kb0 + (long)(j0 + 64)*128;
      char* dst = (char*)Ks[cur^1] + ldsoff;
      #pragma unroll
      for (int r = 0; r < 4; ++r){
        int j = r*16 + srow16;
        int db = sd16 ^ (j & 7);
        gload16(kb + (long)j*128 + db*8, dst + r*4096);
      }
    }
    // swapped QK^T: sa[nt] = K_frag * Q_frag  => S^T tile
    const unsigned short* ksc = Ks[cur];
    f32x4 sa[4] = {};
    __builtin_amdgcn_s_setprio(1);
    #pragma unroll
    for (int nt = 0; nt < 4; ++nt){
      int krow = nt*16 + l15;
      #pragma unroll
      for (int kc = 0; kc < 4; ++kc){
        int db = (kc*4 + g) ^ (krow & 7);
        s16x8 kf = *(const s16x8*)(ksc + krow*128 + db*8);
        sa[nt] = __builtin_amdgcn_mfma_f32_16x16x32_bf16(kf, qf[kc], sa[nt], 0, 0, 0);
      }
    }
    __builtin_amdgcn_s_setprio(0);
    // V prefetch batch B (dt 4..7) — lands during softmax
    s16x8 vfB[4][2];
    #pragma unroll
    for (int dt = 0; dt < 4; ++dt)
      #pragma unroll
      for (int kc = 0; kc < 2; ++kc)
        vfB[dt][kc] = *(const s16x8*)(vbase + (long)(dt+4)*16*S_LEN + j0 + kc*32);
    // mask + in-lane row max (all 16 values belong to q-row iv)
    float tm = -3e38f;
    bool full = (j0 + 63 <= qrb) || ((qrb + 15 < p) && (j0 + 63 < p));
    if (full){
      #pragma unroll
      for (int nt = 0; nt < 4; ++nt)
        #pragma unroll
        for (int rg = 0; rg < 4; ++rg) tm = fmaxf(tm, sa[nt][rg]);
    } else {
      #pragma unroll
      for (int nt = 0; nt < 4; ++nt)
        #pragma unroll
        for (int rg = 0; rg < 4; ++rg){
          int j = j0 + nt*16 + g*4 + rg;
          bool ok = (j <= iv) || ((iv < p) && (j < p));
          float sv = ok ? sa[nt][rg] : -3e38f;
          sa[nt][rg] = sv;
          tm = fmaxf(tm, sv);
        }
    }
    tm = fmaxf(tm, __shfl_xor(tm, 16));
    tm = fmaxf(tm, __shfl_xor(tm, 32));
    // online softmax (log2 domain; scale*log2e pre-folded into Q)
    if (!__all(tm <= mr + 8.0f)){       // T13 defer-max
      float nm = fmaxf(mr, tm);
      float sfv = exp2f(mr - nm);
      mr = nm;
      lr *= sfv;
      float sfO[4];
      #pragma unroll
      for (int rg = 0; rg < 4; ++rg)
        sfO[rg] = __shfl(sfv, (lane & 48) | (g*4 + rg));
      #pragma unroll
      for (int dt = 0; dt < 8; ++dt)
        #pragma unroll
        for (int rg = 0; rg < 4; ++rg) O[dt][rg] *= sfO[rg];
    }
    float rs = 0.f;
    #pragma unroll
    for (int nt = 0; nt < 4; ++nt)
      #pragma unroll
      for (int rg = 0; rg < 4; ++rg){
        float e = exp2f(sa[nt][rg] - mr);
        sa[nt][rg] = e;
        rs += e;
      }
    rs += __shfl_xor(rs, 16);
    rs += __shfl_xor(rs, 32);
    lr += rs;
    // pack P rows to bf16 pairs
    unsigned int u[4][2];
    #pragma unroll
    for (int nt = 0; nt < 4; ++nt)
      #pragma unroll
      for (int hh = 0; hh < 2; ++hh){
        float lo = sa[nt][2*hh], hi = sa[nt][2*hh+1];
        unsigned int r;
        asm("v_cvt_pk_bf16_f32 %0, %1, %2" : "=v"(r) : "v"(lo), "v"(hi));
        u[nt][hh] = r;
      }
    // redistribute into PV A-fragments
    s16x8 pf[2];
    #pragma unroll
    for (int kc = 0; kc < 2; ++kc){
      u32x4 w;
      #pragma unroll
      for (int j = 0; j < 4; ++j){
        int srcl = (((2*g + (j>>1)) & 3) << 4) | l15;
        int va = __shfl((int)u[2*kc][j&1],   srcl);
        int vb = __shfl((int)u[2*kc+1][j&1], srcl);
        w[j] = (unsigned int)((g & 2) ? vb : va);
      }
      pf[kc] = __builtin_bit_cast(s16x8, w);
    }
    // PV from prefetched registers
    __builtin_amdgcn_s_setprio(1);
    #pragma unroll
    for (int dt = 0; dt < 4; ++dt)
      #pragma unroll
      for (int kc = 0; kc < 2; ++kc)
        O[dt] = __builtin_amdgcn_mfma_f32_16x16x32_bf16(pf[kc], vfA[dt][kc], O[dt], 0, 0, 0);
    #pragma unroll
    for (int dt = 4; dt < 8; ++dt)
      #pragma unroll
      for (int kc = 0; kc < 2; ++kc)
        O[dt] = __builtin_amdgcn_mfma_f32_16x16x32_bf16(pf[kc], vfB[dt-4][kc], O[dt], 0, 0, 0);
    __builtin_amdgcn_s_setprio(0);
    __syncthreads();   // drains next-tile stage + frees Ks[cur]
    cur ^= 1;
  }

  if (!split){
    // epilogue: redistribute 1/lr from l15-domain to O-domain, write normalized
    float inv = 1.0f / lr;
    float invO[4];
    #pragma unroll
    for (int rg = 0; rg < 4; ++rg)
      invO[rg] = __shfl(inv, (lane & 48) | (g*4 + rg));
    #pragma unroll
    for (int dt = 0; dt < 8; ++dt)
      #pragma unroll
      for (int rg = 0; rg < 4; ++rg){
        int row = qrb + g*4 + rg;
        int col = h*128 + dt*16 + l15;
        attn_out[(long)(b*S_LEN + row)*DIMM + col] = f2bf(O[dt][rg]*invO[rg]);
      }
  } else {
    // write unnormalized partial: [64][128] f32 O + per-row (m,l) at offset 8192
    float* pb = part + ((((long)b*NH + h)*16 + (qt - 16))*2 + chunk) * 8320;
    #pragma unroll
    for (int dt = 0; dt < 8; ++dt)
      #pragma unroll
      for (int rg = 0; rg < 4; ++rg)
        pb[(wave*16 + g*4 + rg)*128 + dt*16 + l15] = O[dt][rg];
    if (g == 0){
      pb[8192 + (wave*16 + l15)*2 + 0] = mr;
      pb[8192 + (wave*16 + l15)*2 + 1] = lr;
    }
  }
}

// ---------------- merge the two KV-chunk partials for qt in [16,32) ----------------
// grid 512 = 16 qti x 32 bh; block 256: thread = (row 0..63) x (quarter 0..3 of 128 cols)
__global__ __launch_bounds__(256) void attn_merge(const float* __restrict__ part,
                                                  unsigned short* __restrict__ attn_out){
  int bid = blockIdx.x;
  int qti = bid >> 5;                 // 0..15 -> qt = 16+qti
  int bh = bid & 31;
  int h = bh & 15, b = bh >> 4;
  const float* p0 = part + ((((long)b*NH + h)*16 + qti)*2 + 0) * 8320;
  const float* p1 = p0 + 8320;
  int t = threadIdx.x;
  int r = t >> 2, qd = t & 3;
  float m0 = p0[8192 + r*2], l0 = p0[8192 + r*2 + 1];
  float m1 = p1[8192 + r*2], l1 = p1[8192 + r*2 + 1];
  float m  = fmaxf(m0, m1);
  float s0 = exp2f(m0 - m), s1 = exp2f(m1 - m);
  float inv = 1.0f / (l0*s0 + l1*s1);
  float a0 = s0*inv, a1 = s1*inv;
  int row = (16 + qti)*64 + r;
  const float4* x0 = (const float4*)(p0 + r*128 + qd*32);
  const float4* x1 = (const float4*)(p1 + r*128 + qd*32);
  unsigned short* w = attn_out + (long)(b*S_LEN + row)*DIMM + h*128 + qd*32;
  #pragma unroll
  for (int i = 0; i < 4; ++i){
    float4 ya = x0[2*i],   yb = x0[2*i+1];
    float4 za = x1[2*i],   zb = x1[2*i+1];
    u16x8 o;
    o[0] = f2bf(ya.x*a0 + za.x*a1);
    o[1] = f2bf(ya.y*a0 + za.y*a1);
    o[2] = f2bf(ya.z*a0 + za.z*a1);
    o[3] = f2bf(ya.w*a0 + za.w*a1);
    o[4] = f2bf(yb.x*a0 + zb.x*a1);
    o[5] = f2bf(yb.y*a0 + zb.y*a1);
    o[6] = f2bf(yb.z*a0 + zb.z*a1);
    o[7] = f2bf(yb.w*a0 + zb.w*a1);
    *(u16x8*)(w + i*8) = o;
  }
}

extern "C" void kernel_launch(void* const* d_in, const int* in_sizes, int n_in,
                              void* d_out, int out_size, void* d_ws, size_t ws_size,
                              hipStream_t stream){
  const float* x    = (const float*)d_in[0];
  const float* cosb = (const float*)d_in[1];
  const float* sinb = (const float*)d_in[2];
  const float* wq   = (const float*)d_in[3];
  const float* wk   = (const float*)d_in[4];
  const float* wv   = (const float*)d_in[5];
  const float* wo   = (const float*)d_in[6];
  const float* qg   = (const float*)d_in[7];
  const float* kg   = (const float*)d_in[8];
  const int*   pp   = (const int*)d_in[9];

  char* ws = (char*)d_ws;
  unsigned short* xb    = (unsigned short*)(ws);                 // 4096x2048 bf16
  unsigned short* wqkvb = (unsigned short*)(ws + 16777216);      // 2560x2048 bf16
  unsigned short* wob   = (unsigned short*)(ws + 27262976);      // 2048x2048 bf16
  float*          qkv   = (float*)(ws + 35651584);               // 4096x2560 f32
  unsigned short* qat   = (unsigned short*)(ws + 77594624);      // [B,16,S,128]
  unsigned short* kat   = (unsigned short*)(ws + 94371840);      // [B,2,S,128]
  unsigned short* vt    = (unsigned short*)(ws + 96468992);      // [B,2,128,S]
  unsigned short* aout  = (unsigned short*)(ws + 98566144);      // [B,S,2048]
  float*          part  = (float*)(ws + 35651584);               // aliases qkv (dead by attn): 34.1MB

  cvt_bf16<<<8388608/2048, 256, 0, stream>>>(x,  xb, 8388608);
  cvt_bf16<<<4194304/2048, 256, 0, stream>>>(wq, wqkvb, 4194304);
  cvt_bf16<<< 524288/2048, 256, 0, stream>>>(wk, wqkvb + 4194304, 524288);
  cvt_bf16<<< 524288/2048, 256, 0, stream>>>(wv, wqkvb + 4718592, 524288);
  cvt_bf16<<<4194304/2048, 256, 0, stream>>>(wo, wob, 4194304);

  gemm_bt<<<dim3(2560/128, 4096/128), 256, 0, stream>>>(xb, wqkvb, qkv, 4096, 2560, 2048);
  normrope<<<73728/4, 256, 0, stream>>>(qkv, cosb, sinb, qg, kg, qat, kat);
  vtrans<<<128, 256, 0, stream>>>(qkv, vt);
  attn_fwd<<<1536, 256, 0, stream>>>(qat, kat, vt, aout, part, pp);
  attn_merge<<<512, 256, 0, stream>>>(part, aout);
  gemm_bt<<<dim3(2048/128, 4096/128), 256, 0, stream>>>(aout, wob, (float*)d_out, 4096, 2048, 2048);
}

// Round 9
// 266.748 us; speedup vs baseline: 2.0709x; 1.2193x over previous
//
#include <hip/hip_runtime.h>
#include <stdint.h>

#define S_LEN 2048
#define DIMM  2048
#define NH    16
#define NKV   2

typedef __attribute__((ext_vector_type(8)))  short s16x8;
typedef __attribute__((ext_vector_type(8)))  unsigned short u16x8;
typedef __attribute__((ext_vector_type(4)))  float f32x4;
typedef __attribute__((ext_vector_type(16))) float f32x16;
typedef __attribute__((ext_vector_type(4)))  unsigned int u32x4;

__device__ __forceinline__ unsigned short f2bf(float f){
  unsigned int u = __builtin_bit_cast(unsigned int, f);
  u += 0x7fffu + ((u >> 16) & 1u);
  return (unsigned short)(u >> 16);
}

__device__ __forceinline__ unsigned int cvtpk(float lo, float hi){
  unsigned int r;
  asm("v_cvt_pk_bf16_f32 %0, %1, %2" : "=v"(r) : "v"(lo), "v"(hi));
  return r;
}

__device__ __forceinline__ void gload16(const void* g, void* l){
  __builtin_amdgcn_global_load_lds(
      (const __attribute__((address_space(1))) unsigned int*)g,
      (__attribute__((address_space(3))) unsigned int*)l, 16, 0, 0);
}

// ---------------- fp32 -> bf16 convert ----------------
__global__ __launch_bounds__(256) void cvt_bf16(const float* __restrict__ src,
                                                unsigned short* __restrict__ dst, int n){
  int i = (blockIdx.x * 256 + threadIdx.x) * 8;
  if (i >= n) return;
  const float4* s4 = (const float4*)(src + i);
  float4 a = s4[0], b = s4[1];
  u16x8 o;
  o[0]=f2bf(a.x); o[1]=f2bf(a.y); o[2]=f2bf(a.z); o[3]=f2bf(a.w);
  o[4]=f2bf(b.x); o[5]=f2bf(b.y); o[6]=f2bf(b.z); o[7]=f2bf(b.w);
  *(u16x8*)(dst + i) = o;
}

// ---------------- C = A(bf16,[M,K]) @ W(bf16,[N,K])^T -> fp32 [M,N] ----------------
__global__ __launch_bounds__(256) void gemm_bt(const unsigned short* __restrict__ A,
                                               const unsigned short* __restrict__ W,
                                               float* __restrict__ C,
                                               int M, int N, int K){
  __shared__ __attribute__((aligned(16))) unsigned short As[128*64];
  __shared__ __attribute__((aligned(16))) unsigned short Bs[128*64];
  const int t = threadIdx.x;
  const int lane = t & 63, wave = t >> 6;
  const int l15 = lane & 15, g = lane >> 4;
  const int lid = blockIdx.y * gridDim.x + blockIdx.x;
  const int cpx = (gridDim.x * gridDim.y) >> 3;
  const int swz = (lid & 7) * cpx + (lid >> 3);
  const int m0 = (swz / gridDim.x) * 128, n0 = (swz % gridDim.x) * 128;
  const int wm = (wave >> 1) * 64, wn = (wave & 1) * 64;
  const int srow = t >> 3, sdblk = t & 7;
  const long ldsoff = (long)(t >> 6) * 1024;
  f32x4 acc[4][4] = {};
  for (int k0 = 0; k0 < K; k0 += 64){
    __syncthreads();
    #pragma unroll
    for (int r = 0; r < 4; ++r){
      int row = r*32 + srow;
      int db  = sdblk ^ (row & 7);
      gload16(A + (long)(m0+row)*K + k0 + db*8, (char*)As + r*4096 + ldsoff);
    }
    #pragma unroll
    for (int r = 0; r < 4; ++r){
      int row = r*32 + srow;
      int db  = sdblk ^ (row & 7);
      gload16(W + (long)(n0+row)*K + k0 + db*8, (char*)Bs + r*4096 + ldsoff);
    }
    __syncthreads();
    s16x8 af[4][2], bfr[4][2];
    #pragma unroll
    for (int mi = 0; mi < 4; ++mi)
      #pragma unroll
      for (int kc = 0; kc < 2; ++kc){
        int row = wm + mi*16 + l15;
        int db = (kc*4 + g) ^ (row & 7);
        af[mi][kc] = *(const s16x8*)(As + row*64 + db*8);
      }
    #pragma unroll
    for (int ni = 0; ni < 4; ++ni)
      #pragma unroll
      for (int kc = 0; kc < 2; ++kc){
        int row = wn + ni*16 + l15;
        int db = (kc*4 + g) ^ (row & 7);
        bfr[ni][kc] = *(const s16x8*)(Bs + row*64 + db*8);
      }
    #pragma unroll
    for (int mi = 0; mi < 4; ++mi)
      #pragma unroll
      for (int ni = 0; ni < 4; ++ni)
        #pragma unroll
        for (int kc = 0; kc < 2; ++kc)
          acc[mi][ni] = __builtin_amdgcn_mfma_f32_16x16x32_bf16(af[mi][kc], bfr[ni][kc], acc[mi][ni], 0, 0, 0);
  }
  #pragma unroll
  for (int mi = 0; mi < 4; ++mi)
    #pragma unroll
    for (int ni = 0; ni < 4; ++ni)
      #pragma unroll
      for (int rg = 0; rg < 4; ++rg){
        int row = m0 + wm + mi*16 + g*4 + rg;
        int col = n0 + wn + ni*16 + l15;
        C[(long)row*N + col] = acc[mi][ni][rg];
      }
}

// ---------------- RMSNorm + rotary for Q and K ----------------
// Q gets (1/sqrt(128))*log2(e) folded in => attention exp becomes exp2.
__global__ __launch_bounds__(256) void normrope(const float* __restrict__ qkv,
    const float* __restrict__ cosb, const float* __restrict__ sinb,
    const float* __restrict__ qg, const float* __restrict__ kg,
    unsigned short* __restrict__ q_attn, unsigned short* __restrict__ k_attn){
  int wave = threadIdx.x >> 6, lane = threadIdx.x & 63;
  int rid = blockIdx.x * 4 + wave;
  int d0 = lane * 2;
  const float* src; unsigned short* dst; const float* gm; float sc; int s;
  if (rid < 2*S_LEN*NH){
    int bs = rid >> 4, h = rid & 15;
    int b = bs >> 11; s = bs & 2047;
    src = qkv + (long)bs*2560 + h*128;
    dst = q_attn + ((long)(b*NH + h)*S_LEN + s)*128;
    gm = qg; sc = 0.08838834764831845f * 1.4426950408889634f;
  } else {
    int r2 = rid - 2*S_LEN*NH;
    int bs = r2 >> 1, kv = r2 & 1;
    int b = bs >> 11; s = bs & 2047;
    src = qkv + (long)bs*2560 + 2048 + kv*128;
    dst = k_attn + ((long)(b*NKV + kv)*S_LEN + s)*128;
    gm = kg; sc = 1.0f;
  }
  float2 x = *(const float2*)(src + d0);
  float ss = x.x*x.x + x.y*x.y;
  #pragma unroll
  for (int m = 1; m < 64; m <<= 1) ss += __shfl_xor(ss, m);
  float r = rsqrtf(ss * (1.0f/128.0f) + 1e-6f);
  float2 gv = *(const float2*)(gm + d0);
  float n0 = x.x * r * gv.x, n1 = x.y * r * gv.y;
  float p0 = __shfl_xor(n0, 32), p1 = __shfl_xor(n1, 32);
  float sgn = (d0 < 64) ? -1.f : 1.f;
  float2 c  = *(const float2*)(cosb + (long)s*128 + d0);
  float2 sn = *(const float2*)(sinb + (long)s*128 + d0);
  float o0 = (n0*c.x + sgn*p0*sn.x) * sc;
  float o1 = (n1*c.y + sgn*p1*sn.y) * sc;
  unsigned int pk = (unsigned int)f2bf(o0) | ((unsigned int)f2bf(o1) << 16);
  *(unsigned int*)(dst + d0) = pk;
}

// ---------------- V: [B,S,KV,128] cols of qkv -> bf16 [B,KV,128,S] (transposed) ----------------
__global__ __launch_bounds__(256) void vtrans(const float* __restrict__ qkv,
                                              unsigned short* __restrict__ v_t){
  __shared__ __attribute__((aligned(16))) unsigned short lds[128*72];
  int bid = blockIdx.x;
  int s0 = (bid & 31) * 64;
  int kv = (bid >> 5) & 1;
  int b  = bid >> 6;
  int t = threadIdx.x;
  #pragma unroll
  for (int it = 0; it < 32; ++it){
    int idx = it*256 + t;
    int s = idx >> 7, d = idx & 127;
    float v = qkv[(long)(b*S_LEN + s0 + s)*2560 + 2304 + kv*128 + d];
    lds[d*72 + s] = f2bf(v);
  }
  __syncthreads();
  #pragma unroll
  for (int it = 0; it < 4; ++it){
    int c = it*256 + t;
    int d = c >> 3, s8 = c & 7;
    u16x8 vv = *(const u16x8*)(lds + d*72 + s8*8);
    *(u16x8*)(v_t + ((long)(b*NKV + kv)*128 + d)*S_LEN + s0 + s8*8) = vv;
  }
}

// ---------------- flash attention: 32x32 MFMA, QBLK=32/wave, swapped QK^T ----------------
// grid 512 = 16 qsb (LPT desc) x 32 (b,h); block 256 = 4 waves x 32 q-rows = 128 q/block.
// All blocks resident (2/CU). mfma_32x32x16(K,Q): lane pair (l31, l31+32) holds the full
// 64-k score row of q=qw0+l31. Softmax: 31 in-lane fmax + 1 shfl_xor(32). P->A-frag via
// 16 cvt_pk + 8 v_permlane32_swap (VALU; replaces 16 ds_bpermute). Per-warp kv bound.
__global__ __launch_bounds__(256, 2) void attn_fwd(const unsigned short* __restrict__ q_attn,
    const unsigned short* __restrict__ k_attn, const unsigned short* __restrict__ v_t,
    unsigned short* __restrict__ attn_out, const int* __restrict__ pp){
  __shared__ __attribute__((aligned(16))) unsigned short Ks[2][64*128];
  const int p = pp[0];
  int bid = blockIdx.x;
  int qsb = 15 - (bid >> 5);         // LPT: longest chains dispatch first
  int bh = bid & 31;
  int h = bh & 15, b = bh >> 4;
  int kvh = h >> 3;
  int t = threadIdx.x, wave = t >> 6, lane = t & 63;
  int l31 = lane & 31, hi = lane >> 5;
  int QS = qsb * 128;
  int qw0 = QS + wave*32;            // this wave's 32 q-rows
  const int q = qw0 + l31;           // this lane's q-row (pair with lane^32)
  // Q fragments: B-operand, lane holds Q[q][m*16 + hi*8 .. +8]
  const unsigned short* qb = q_attn + ((long)(b*NH + h)*S_LEN + q)*128 + hi*8;
  s16x8 qf[8];
  #pragma unroll
  for (int m = 0; m < 8; ++m) qf[m] = *(const s16x8*)(qb + m*16);
  f32x16 O[4] = {};                  // O[dt]: q=rowfmla, d=dt*32+l31
  float mr = -3e38f, lr = 0.f;
  int kvend_w = (qw0 + 31 < p) ? ((p > qw0 + 32) ? p : qw0 + 32) : (qw0 + 32);
  int n_w = (kvend_w + 63) >> 6;
  int kvend_b = (QS + 127 < p) ? ((p > QS + 128) ? p : QS + 128) : (QS + 128);
  int n_blk = (kvend_b + 63) >> 6;
  const unsigned short* kb0 = k_attn + ((long)(b*NKV + kvh)*S_LEN)*128;
  const unsigned short* vb0 = v_t + ((long)(b*NKV + kvh)*128)*S_LEN;
  const int srow = t >> 4, sunit = t & 15;   // staging: 16 rows x 16 units per pass
  const long ldsoff = (long)wave * 1024;
  const unsigned short* vbase = vb0 + (long)l31*S_LEN + hi*8;

  // prologue: stage tile 0 into Ks[0] (global src pre-swizzled, LDS linear)
  #pragma unroll
  for (int r = 0; r < 4; ++r){
    int row = r*16 + srow;
    int un  = sunit ^ (row & 15);
    gload16(kb0 + (long)row*128 + un*8, (char*)Ks[0] + r*4096 + ldsoff);
  }
  __syncthreads();
  int buf = 0;

  #pragma unroll 1
  for (int ti = 0; ti < n_blk; ++ti){
    int j0 = ti * 64;
    bool act = ti < n_w;             // warp-uniform
    s16x8 vfA[2][4], vfB[2][4];
    if (act){
      #pragma unroll
      for (int dt = 0; dt < 2; ++dt)
        #pragma unroll
        for (int km = 0; km < 4; ++km)
          vfA[dt][km] = *(const s16x8*)(vbase + (long)dt*32*S_LEN + j0 + km*16);
    }
    if (ti + 1 < n_blk){
      const unsigned short* kb = kb0 + (long)(j0 + 64)*128;
      char* dst = (char*)Ks[buf^1] + ldsoff;
      #pragma unroll
      for (int r = 0; r < 4; ++r){
        int row = r*16 + srow;
        int un  = sunit ^ (row & 15);
        gload16(kb + (long)row*128 + un*8, dst + r*4096);
      }
    }
    if (act){
      // swapped QK^T: sa[kt] = mfma(K_frag, Q_frag) -> D[krow][q]
      const unsigned short* ksc = Ks[buf];
      f32x16 sa[2] = {};
      __builtin_amdgcn_s_setprio(1);
      #pragma unroll
      for (int kt = 0; kt < 2; ++kt){
        int row = kt*32 + l31;
        #pragma unroll
        for (int m = 0; m < 8; ++m){
          int un = (2*m + hi) ^ (row & 15);
          s16x8 kf = *(const s16x8*)(ksc + row*128 + un*8);
          sa[kt] = __builtin_amdgcn_mfma_f32_32x32x16_bf16(kf, qf[m], sa[kt], 0, 0, 0);
        }
      }
      __builtin_amdgcn_s_setprio(0);
      // V prefetch batch B (dt 2,3) — lands during softmax
      #pragma unroll
      for (int dt = 0; dt < 2; ++dt)
        #pragma unroll
        for (int km = 0; km < 4; ++km)
          vfB[dt][km] = *(const s16x8*)(vbase + (long)(dt+2)*32*S_LEN + j0 + km*16);
      // mask + in-lane row max (32 scores of q in this lane; rest in lane^32)
      float tm = -3e38f;
      bool full = (j0 + 63 <= qw0) || ((qw0 + 31 < p) && (j0 + 63 < p));
      if (full){
        #pragma unroll
        for (int kt = 0; kt < 2; ++kt)
          #pragma unroll
          for (int rg = 0; rg < 16; ++rg) tm = fmaxf(tm, sa[kt][rg]);
      } else {
        #pragma unroll
        for (int kt = 0; kt < 2; ++kt)
          #pragma unroll
          for (int rg = 0; rg < 16; ++rg){
            int j = j0 + kt*32 + (rg & 3) + 8*(rg >> 2) + 4*hi;
            bool ok = (j <= q) || ((q < p) && (j < p));
            float sv = ok ? sa[kt][rg] : -3e38f;
            sa[kt][rg] = sv;
            tm = fmaxf(tm, sv);
          }
      }
      tm = fmaxf(tm, __shfl_xor(tm, 32));
      // online softmax (log2 domain)
      if (!__all(tm <= mr + 8.0f)){      // T13 defer-max
        float nm = fmaxf(mr, tm);
        float sfv = exp2f(mr - nm);
        mr = nm;
        lr *= sfv;
        float sfO[16];
        #pragma unroll
        for (int rg = 0; rg < 16; ++rg){
          int qr = (rg & 3) + 8*(rg >> 2) + 4*hi;
          sfO[rg] = __shfl(sfv, qr | (lane & 32));
        }
        #pragma unroll
        for (int dt = 0; dt < 4; ++dt)
          #pragma unroll
          for (int rg = 0; rg < 16; ++rg) O[dt][rg] *= sfO[rg];
      }
      float rs = 0.f;
      #pragma unroll
      for (int kt = 0; kt < 2; ++kt)
        #pragma unroll
        for (int rg = 0; rg < 16; ++rg){
          float e = exp2f(sa[kt][rg] - mr);
          sa[kt][rg] = e;
          rs += e;
        }
      rs += __shfl_xor(rs, 32);
      lr += rs;
      // P -> PV A-frags: per km, 4 cvt_pk + 2 permlane32_swap (in-register transpose)
      __builtin_amdgcn_s_setprio(1);
      #pragma unroll
      for (int km = 0; km < 4; ++km){
        int base = (km & 1) * 8;
        const f32x16& s = sa[km >> 1];
        unsigned int a0 = cvtpk(s[base+0], s[base+1]);
        unsigned int b0 = cvtpk(s[base+4], s[base+5]);
        asm("v_permlane32_swap_b32 %0, %1" : "+v"(a0), "+v"(b0));
        unsigned int a1 = cvtpk(s[base+2], s[base+3]);
        unsigned int b1 = cvtpk(s[base+6], s[base+7]);
        asm("v_permlane32_swap_b32 %0, %1" : "+v"(a1), "+v"(b1));
        u32x4 w; w[0] = a0; w[1] = a1; w[2] = b0; w[3] = b1;
        s16x8 pf = __builtin_bit_cast(s16x8, w);
        #pragma unroll
        for (int dt = 0; dt < 2; ++dt)
          O[dt] = __builtin_amdgcn_mfma_f32_32x32x16_bf16(pf, vfA[dt][km], O[dt], 0, 0, 0);
        #pragma unroll
        for (int dt = 2; dt < 4; ++dt)
          O[dt] = __builtin_amdgcn_mfma_f32_32x32x16_bf16(pf, vfB[dt-2][km], O[dt], 0, 0, 0);
      }
      __builtin_amdgcn_s_setprio(0);
    }
    __syncthreads();   // drains next-tile stage + frees Ks[buf]
    buf ^= 1;
  }
  // epilogue: redistribute 1/lr (q=l31 domain) to O rows, write bf16
  float inv = 1.0f / lr;
  float invO[16];
  #pragma unroll
  for (int rg = 0; rg < 16; ++rg){
    int qr = (rg & 3) + 8*(rg >> 2) + 4*hi;
    invO[rg] = __shfl(inv, qr | (lane & 32));
  }
  #pragma unroll
  for (int dt = 0; dt < 4; ++dt)
    #pragma unroll
    for (int rg = 0; rg < 16; ++rg){
      int row = qw0 + (rg & 3) + 8*(rg >> 2) + 4*hi;
      int col = h*128 + dt*32 + l31;
      attn_out[(long)(b*S_LEN + row)*DIMM + col] = f2bf(O[dt][rg]*invO[rg]);
    }
}

extern "C" void kernel_launch(void* const* d_in, const int* in_sizes, int n_in,
                              void* d_out, int out_size, void* d_ws, size_t ws_size,
                              hipStream_t stream){
  const float* x    = (const float*)d_in[0];
  const float* cosb = (const float*)d_in[1];
  const float* sinb = (const float*)d_in[2];
  const float* wq   = (const float*)d_in[3];
  const float* wk   = (const float*)d_in[4];
  const float* wv   = (const float*)d_in[5];
  const float* wo   = (const float*)d_in[6];
  const float* qg   = (const float*)d_in[7];
  const float* kg   = (const float*)d_in[8];
  const int*   pp   = (const int*)d_in[9];

  char* ws = (char*)d_ws;
  unsigned short* xb    = (unsigned short*)(ws);                 // 4096x2048 bf16
  unsigned short* wqkvb = (unsigned short*)(ws + 16777216);      // 2560x2048 bf16
  unsigned short* wob   = (unsigned short*)(ws + 27262976);      // 2048x2048 bf16
  float*          qkv   = (float*)(ws + 35651584);               // 4096x2560 f32
  unsigned short* qat   = (unsigned short*)(ws + 77594624);      // [B,16,S,128]
  unsigned short* kat   = (unsigned short*)(ws + 94371840);      // [B,2,S,128]
  unsigned short* vt    = (unsigned short*)(ws + 96468992);      // [B,2,128,S]
  unsigned short* aout  = (unsigned short*)(ws + 98566144);      // [B,S,2048]

  cvt_bf16<<<8388608/2048, 256, 0, stream>>>(x,  xb, 8388608);
  cvt_bf16<<<4194304/2048, 256, 0, stream>>>(wq, wqkvb, 4194304);
  cvt_bf16<<< 524288/2048, 256, 0, stream>>>(wk, wqkvb + 4194304, 524288);
  cvt_bf16<<< 524288/2048, 256, 0, stream>>>(wv, wqkvb + 4718592, 524288);
  cvt_bf16<<<4194304/2048, 256, 0, stream>>>(wo, wob, 4194304);

  gemm_bt<<<dim3(2560/128, 4096/128), 256, 0, stream>>>(xb, wqkvb, qkv, 4096, 2560, 2048);
  normrope<<<73728/4, 256, 0, stream>>>(qkv, cosb, sinb, qg, kg, qat, kat);
  vtrans<<<128, 256, 0, stream>>>(qkv, vt);
  attn_fwd<<<512, 256, 0, stream>>>(qat, kat, vt, aout, pp);
  gemm_bt<<<dim3(2048/128, 4096/128), 256, 0, stream>>>(aout, wob, (float*)d_out, 4096, 2048, 2048);
}